// Round 1
// baseline (363.775 us; speedup 1.0000x reference)
//
#include <hip/hip_runtime.h>

// out[b,c,h,w] = alpha[slot[b,h,w], c] * x[b,c,h,w] + beta[slot[b,h,w], c]
// x: [B, C, H, W] f32; alpha/beta: [S, C] f32; slot: [B, H, W] i32
// B=16, C=256, S=256, H=W=112 -> HW=12544

#define NUM_SLOTS 256
#define CHANNELS  256
#define TC        16            // channels per block (c-tile)
#define HW        12544         // 112*112
#define HW4       3136          // HW/4 (float4 spatial positions)
#define SPLITS    4             // spatial splits per (b, c-tile)
#define CHUNK     784           // HW4 / SPLITS

__global__ __launch_bounds__(256) void slot_affine_kernel(
    const float* __restrict__ x,
    const float* __restrict__ alpha,
    const float* __restrict__ beta,
    const int*   __restrict__ slot,
    float*       __restrict__ out)
{
    // interleaved {alpha, beta} for this block's 16 channels, all 256 slots: 32 KB
    __shared__ float2 tab[TC][NUM_SLOTS];

    const int t     = threadIdx.x;   // 0..255
    const int split = blockIdx.x;    // 0..SPLITS-1
    const int ct    = blockIdx.y;    // 0..C/TC-1
    const int b     = blockIdx.z;    // 0..B-1
    const int c0    = ct * TC;

    // ---- stage tables: thread t owns slot row s = t (one row per thread) ----
    {
        const float4* arow = reinterpret_cast<const float4*>(alpha + (size_t)t * CHANNELS + c0);
        const float4* brow = reinterpret_cast<const float4*>(beta  + (size_t)t * CHANNELS + c0);
        #pragma unroll
        for (int k = 0; k < TC / 4; ++k) {
            float4 a4 = arow[k];
            float4 b4 = brow[k];
            // transposed write: consecutive lanes -> consecutive slots -> stride-2 banks (free)
            tab[4 * k + 0][t] = make_float2(a4.x, b4.x);
            tab[4 * k + 1][t] = make_float2(a4.y, b4.y);
            tab[4 * k + 2][t] = make_float2(a4.z, b4.z);
            tab[4 * k + 3][t] = make_float2(a4.w, b4.w);
        }
    }
    __syncthreads();

    const int4* slot4 = reinterpret_cast<const int4*>(slot + (size_t)b * HW);
    const int pbase = split * CHUNK;
    const int pend  = pbase + CHUNK;

    for (int p = pbase + t; p < pend; p += 256) {
        const int4 s4 = slot4[p];
        #pragma unroll
        for (int ci = 0; ci < TC; ++ci) {
            const size_t plane = (size_t)(b * CHANNELS + c0 + ci) * HW;
            const float4* xp = reinterpret_cast<const float4*>(x + plane);
            float4*       op = reinterpret_cast<float4*>(out + plane);
            const float4 xv = xp[p];
            const float2 t0 = tab[ci][s4.x];
            const float2 t1 = tab[ci][s4.y];
            const float2 t2 = tab[ci][s4.z];
            const float2 t3 = tab[ci][s4.w];
            float4 r;
            r.x = fmaf(t0.x, xv.x, t0.y);
            r.y = fmaf(t1.x, xv.y, t1.y);
            r.z = fmaf(t2.x, xv.z, t2.y);
            r.w = fmaf(t3.x, xv.w, t3.y);
            op[p] = r;
        }
    }
}

extern "C" void kernel_launch(void* const* d_in, const int* in_sizes, int n_in,
                              void* d_out, int out_size, void* d_ws, size_t ws_size,
                              hipStream_t stream) {
    const float* x     = (const float*)d_in[0];
    const float* alpha = (const float*)d_in[1];
    const float* beta  = (const float*)d_in[2];
    const int*   slot  = (const int*)d_in[3];
    float* out = (float*)d_out;

    const int B = in_sizes[0] / (CHANNELS * HW);   // 16

    dim3 grid(SPLITS, CHANNELS / TC, B);           // 4 x 16 x 16 = 1024 blocks
    dim3 block(256);
    slot_affine_kernel<<<grid, block, 0, stream>>>(x, alpha, beta, slot, out);
}

// Round 3
// 354.357 us; speedup vs baseline: 1.0266x; 1.0266x over previous
//
#include <hip/hip_runtime.h>

// out[b,c,h,w] = alpha[slot[b,h,w], c] * x[b,c,h,w] + beta[slot[b,h,w], c]
// x: [B, C, H, W] f32; alpha/beta: [S, C] f32; slot: [B, H, W] i32
// B=16, C=256, S=256, H=W=112 -> HW=12544
//
// R3: R1 control flow (proven correct under graph capture) + the two
// latency-regime fixes: TC=8 (16 KB LDS -> 2048 blocks) and two-phase
// batched xv[8] plane loads (8 loads in flight per wave). NO launch_bounds
// min-waves clamp (R2's forced spill is the prime suspect for the
// post-timing divergence), no manual slot prefetch.

#define NUM_SLOTS 256
#define CHANNELS  256
#define TC        8             // channels per block (c-tile)
#define HW        12544         // 112*112
#define HW4       3136          // HW/4 (float4 spatial positions)
#define SPLITS    4             // spatial splits per (b, c-tile)
#define CHUNK     784           // HW4 / SPLITS

__global__ __launch_bounds__(256) void slot_affine_kernel(
    const float* __restrict__ x,
    const float* __restrict__ alpha,
    const float* __restrict__ beta,
    const int*   __restrict__ slot,
    float*       __restrict__ out)
{
    // interleaved {alpha, beta} for this block's 8 channels, all 256 slots: 16 KB
    __shared__ float2 tab[TC][NUM_SLOTS];

    const int t     = threadIdx.x;   // 0..255
    const int split = blockIdx.x;    // 0..SPLITS-1
    const int ct    = blockIdx.y;    // 0..C/TC-1
    const int b     = blockIdx.z;    // 0..B-1
    const int c0    = ct * TC;

    // ---- stage tables: thread t owns slot row s = t ----
    {
        const float4* arow = reinterpret_cast<const float4*>(alpha + (size_t)t * CHANNELS + c0);
        const float4* brow = reinterpret_cast<const float4*>(beta  + (size_t)t * CHANNELS + c0);
        #pragma unroll
        for (int k = 0; k < TC / 4; ++k) {
            float4 a4 = arow[k];
            float4 b4 = brow[k];
            // consecutive lanes -> consecutive slots -> 2-lanes/bank (free)
            tab[4 * k + 0][t] = make_float2(a4.x, b4.x);
            tab[4 * k + 1][t] = make_float2(a4.y, b4.y);
            tab[4 * k + 2][t] = make_float2(a4.z, b4.z);
            tab[4 * k + 3][t] = make_float2(a4.w, b4.w);
        }
    }
    __syncthreads();

    const int4*   slot4 = reinterpret_cast<const int4*>(slot + (size_t)b * HW);
    const float4* xp    = reinterpret_cast<const float4*>(x   + ((size_t)b * CHANNELS + c0) * HW);
    float4*       op    = reinterpret_cast<float4*>      (out + ((size_t)b * CHANNELS + c0) * HW);

    const int pbase = split * CHUNK;
    const int pend  = pbase + CHUNK;

    for (int p = pbase + t; p < pend; p += 256) {
        const int4 s4 = slot4[p];

        // phase 1: all 8 plane loads issued before any use (8 in flight)
        float4 xv[TC];
        #pragma unroll
        for (int ci = 0; ci < TC; ++ci)
            xv[ci] = xp[(size_t)ci * HW4 + p];

        // phase 2: LDS table gather + fma + store per channel
        #pragma unroll
        for (int ci = 0; ci < TC; ++ci) {
            const float2 t0 = tab[ci][s4.x];
            const float2 t1 = tab[ci][s4.y];
            const float2 t2 = tab[ci][s4.z];
            const float2 t3 = tab[ci][s4.w];
            float4 r;
            r.x = fmaf(t0.x, xv[ci].x, t0.y);
            r.y = fmaf(t1.x, xv[ci].y, t1.y);
            r.z = fmaf(t2.x, xv[ci].z, t2.y);
            r.w = fmaf(t3.x, xv[ci].w, t3.y);
            op[(size_t)ci * HW4 + p] = r;
        }
    }
}

extern "C" void kernel_launch(void* const* d_in, const int* in_sizes, int n_in,
                              void* d_out, int out_size, void* d_ws, size_t ws_size,
                              hipStream_t stream) {
    const float* x     = (const float*)d_in[0];
    const float* alpha = (const float*)d_in[1];
    const float* beta  = (const float*)d_in[2];
    const int*   slot  = (const int*)d_in[3];
    float* out = (float*)d_out;

    const int B = in_sizes[0] / (CHANNELS * HW);   // 16

    dim3 grid(SPLITS, CHANNELS / TC, B);           // 4 x 32 x 16 = 2048 blocks
    dim3 block(256);
    slot_affine_kernel<<<grid, block, 0, stream>>>(x, alpha, beta, slot, out);
}